// Round 2
// baseline (471.389 us; speedup 1.0000x reference)
//
#include <hip/hip_runtime.h>

#define NB      20    // NUM_BINS
#define NBOUND  19    // NUM_BINS - 1
#define ED      768   // EMBED_DIM
#define EPS     1e-8f
#define RPB     128   // rows per block

// Two-phase block: Phase A computes per-row metadata with full MLP
// (19 independent register loads per thread, register-only scan);
// Phase B streams coalesced float4 stores with no long dependent chains.
__global__ __launch_bounds__(256) void sde_kernel(
    const float* __restrict__ values,
    const int*   __restrict__ code_ids,
    const float* __restrict__ boundaries,
    const float* __restrict__ embed_table,
    float*       __restrict__ out,
    int batch)
{
    __shared__ float s_alpha[RPB];
    __shared__ int   s_lo[RPB];
    __shared__ int   s_hi[RPB];

    const int tid  = threadIdx.x;
    const int base = blockIdx.x * RPB;

    // ---------- Phase A: metadata for RPB rows (threads 0..RPB-1) ----------
    if (tid < RPB && base + tid < batch) {
        const int b = base + tid;
        const float v = values[b];
        const int   c = code_ids[b];
        const float* __restrict__ br = boundaries + (size_t)c * NBOUND;

        // All 19 boundaries into registers (constant indices -> no scratch),
        // independent loads -> full memory-level parallelism.
        float bb[NBOUND];
        #pragma unroll
        for (int j = 0; j < NBOUND; ++j) bb[j] = br[j];

        // searchsorted(side='left'): count of boundaries strictly < v
        int idx = 0;
        #pragma unroll
        for (int j = 0; j < NBOUND; ++j) idx += (bb[j] < v) ? 1 : 0;

        // lo_b = bb[clip(idx-1,0,18)] : last boundary < v, else bb[0]
        float lo_b = bb[0];
        #pragma unroll
        for (int j = 1; j < NBOUND; ++j) if (bb[j] < v) lo_b = bb[j];

        // hi_b = bb[clip(idx,0,18)] : first boundary >= v, else bb[18]
        float hi_b = bb[NBOUND - 1];
        #pragma unroll
        for (int j = NBOUND - 2; j >= 0; --j) if (bb[j] >= v) hi_b = bb[j];

        const bool interior = (idx > 0) && (idx < NB - 1);
        const float denom = hi_b - lo_b;
        const bool tiny = fabsf(denom) < EPS;

        float alpha = (v - lo_b) / (tiny ? 1.0f : denom);
        alpha = fminf(fmaxf(alpha, 0.0f), 1.0f);
        if (tiny)      alpha = 0.5f;
        if (!interior) alpha = 0.0f;

        const int lower = (idx == 0) ? 0 : ((idx >= NB - 1) ? NB - 1 : idx - 1);
        const int upper = interior ? idx : lower;

        s_alpha[tid] = alpha;
        s_lo[tid]    = lower * ED;   // pre-scaled row offsets
        s_hi[tid]    = upper * ED;
    }
    __syncthreads();

    // ---------- Phase B: streaming blend+store, 32 rows per wave ----------
    const int wave = tid >> 6;
    const int lane = tid & 63;

    const int rows = (batch - base < RPB) ? (batch - base) : RPB;
    #pragma unroll 2
    for (int r = wave; r < rows; r += 4) {
        const float a  = s_alpha[r];        // same addr across wave -> LDS broadcast
        const float om = 1.0f - a;
        const float4* __restrict__ tlo = (const float4*)(embed_table + s_lo[r]);
        const float4* __restrict__ thi = (const float4*)(embed_table + s_hi[r]);
        float4* __restrict__ orow = (float4*)(out + (size_t)(base + r) * ED) + lane;

        #pragma unroll
        for (int k = 0; k < 3; ++k) {
            const int s = lane + k * 64;
            const float4 e0 = tlo[s];       // L1/L2-resident (table is 60 KB)
            const float4 e1 = thi[s];
            float4 o;
            o.x = om * e0.x + a * e1.x;
            o.y = om * e0.y + a * e1.y;
            o.z = om * e0.z + a * e1.z;
            o.w = om * e0.w + a * e1.w;
            orow[k * 64] = o;
        }
    }
}

extern "C" void kernel_launch(void* const* d_in, const int* in_sizes, int n_in,
                              void* d_out, int out_size, void* d_ws, size_t ws_size,
                              hipStream_t stream)
{
    const float* values     = (const float*)d_in[0];
    const int*   code_ids   = (const int*)  d_in[1];
    const float* boundaries = (const float*)d_in[2];
    const float* embed      = (const float*)d_in[3];
    float*       out        = (float*)d_out;

    const int batch  = in_sizes[0];
    const int blocks = (batch + RPB - 1) / RPB;   // 1024 blocks for batch=131072

    sde_kernel<<<blocks, 256, 0, stream>>>(values, code_ids, boundaries, embed, out, batch);
}